// Round 1
// baseline (294.708 us; speedup 1.0000x reference)
//
#include <hip/hip_runtime.h>
#include <stdint.h>

typedef __attribute__((ext_vector_type(8))) short shortx8;
typedef __attribute__((ext_vector_type(4))) float floatx4;
typedef unsigned short bf16_t;

#define NH 16
#define HD 64
#define SEQ 2048
#define BATCH 2
#define DM 1024
#define DM3 3072
#define MTOT 4096  // BATCH*SEQ

__device__ __forceinline__ bf16_t f2bf(float f) {
    unsigned int u = __float_as_uint(f);
    u += 0x7fff + ((u >> 16) & 1);   // RTN-even
    return (bf16_t)(u >> 16);
}

// ---------------- tokens fp32 -> bf16 (same layout) ----------------
__global__ __launch_bounds__(256) void conv_tokens(const float* __restrict__ in,
                                                   bf16_t* __restrict__ out) {
    int idx = blockIdx.x * 256 + threadIdx.x;  // 8 elements per thread
    float4 a = ((const float4*)in)[idx * 2];
    float4 b = ((const float4*)in)[idx * 2 + 1];
    uint4 o;
    o.x = (unsigned)f2bf(a.x) | ((unsigned)f2bf(a.y) << 16);
    o.y = (unsigned)f2bf(a.z) | ((unsigned)f2bf(a.w) << 16);
    o.z = (unsigned)f2bf(b.x) | ((unsigned)f2bf(b.y) << 16);
    o.w = (unsigned)f2bf(b.z) | ((unsigned)f2bf(b.w) << 16);
    ((uint4*)out)[idx] = o;
}

// ---------------- w_qkv [1024][3072] fp32 -> wt [3072][1024] bf16 ----------------
__global__ __launch_bounds__(256) void conv_w(const float* __restrict__ w,
                                              bf16_t* __restrict__ wt) {
    __shared__ bf16_t t[64 * 65];
    const int n0 = blockIdx.x * 64;  // 48 blocks
    const int k0 = blockIdx.y * 64;  // 16 blocks
    const int tid = threadIdx.x;
    for (int i = 0; i < 16; i++) {
        int idx = i * 256 + tid;
        int r = idx >> 6, c = idx & 63;
        t[r * 65 + c] = f2bf(w[(k0 + r) * DM3 + n0 + c]);
    }
    __syncthreads();
    for (int i = 0; i < 16; i++) {
        int idx = i * 256 + tid;
        int r = idx >> 6, c = idx & 63;
        wt[(n0 + r) * DM + k0 + c] = t[c * 65 + r];
    }
}

// ---------------- QKV GEMM: [4096x1024] @ wt^T -> Q/K/Vt bf16 ----------------
// A: tokens_bf16 [4096][1024] row-major; Bt: wt [3072][1024] (i.e. B^T)
__global__ __launch_bounds__(256) void qkv_gemm(const bf16_t* __restrict__ A,
                                                const bf16_t* __restrict__ Bt,
                                                const float* __restrict__ bias,
                                                bf16_t* __restrict__ Qo,
                                                bf16_t* __restrict__ Ko,
                                                bf16_t* __restrict__ Vto) {
    __shared__ __align__(16) bf16_t As[128 * 64];
    __shared__ __align__(16) bf16_t Bs[128 * 64];
    const int m0 = blockIdx.x * 128;
    const int n0 = blockIdx.y * 128;
    const int tid = threadIdx.x;
    const int wave = tid >> 6, lane = tid & 63;
    const int quad = lane >> 4, l16 = lane & 15;
    const int wm = (wave & 1) * 64, wn = (wave >> 1) * 64;
    floatx4 acc[4][4] = {};

    for (int kt = 0; kt < DM; kt += 64) {
        __syncthreads();
        for (int i = 0; i < 4; i++) {
            int idx = i * 256 + tid;          // uint4 index within tile
            int row = idx >> 3, c8 = (idx & 7) * 8;
            *(uint4*)&As[row * 64 + c8] = *(const uint4*)&A[(m0 + row) * DM + kt + c8];
            *(uint4*)&Bs[row * 64 + c8] = *(const uint4*)&Bt[(n0 + row) * DM + kt + c8];
        }
        __syncthreads();
        for (int ks = 0; ks < 2; ks++) {
            shortx8 af[4], bfr[4];
            for (int t = 0; t < 4; t++)
                af[t] = *(const shortx8*)&As[(wm + t * 16 + l16) * 64 + ks * 32 + quad * 8];
            for (int t = 0; t < 4; t++)
                bfr[t] = *(const shortx8*)&Bs[(wn + t * 16 + l16) * 64 + ks * 32 + quad * 8];
            for (int i = 0; i < 4; i++)
                for (int j = 0; j < 4; j++)
                    acc[i][j] = __builtin_amdgcn_mfma_f32_16x16x32_bf16(af[i], bfr[j], acc[i][j], 0, 0, 0);
        }
    }
    // epilogue: bias add, scale Q by 0.125, scatter to head layouts
    for (int i = 0; i < 4; i++)
        for (int j = 0; j < 4; j++)
            for (int r = 0; r < 4; r++) {
                int m = m0 + wm + i * 16 + quad * 4 + r;   // token row
                int n = n0 + wn + j * 16 + l16;            // qkv channel
                float v = acc[i][j][r] + bias[n];
                int part = n >> 10;         // 0=q 1=k 2=v
                int rr = n & 1023;
                int h = rr >> 6, d = rr & 63;
                int b = m >> 11, pos = m & 2047;
                if (part == 0) {
                    Qo[((b * NH + h) * SEQ + pos) * HD + d] = f2bf(v * 0.125f);
                } else if (part == 1) {
                    Ko[((b * NH + h) * SEQ + pos) * HD + d] = f2bf(v);
                } else {
                    Vto[((b * NH + h) * HD + d) * SEQ + pos] = f2bf(v);
                }
            }
}

// ---------------- flash attention: block = (b,h, 128 q-rows), 64-key tiles ----------------
__global__ __launch_bounds__(256) void attn(const bf16_t* __restrict__ Q,
                                            const bf16_t* __restrict__ K,
                                            const bf16_t* __restrict__ Vt,
                                            float* __restrict__ out) {
    __shared__ __align__(16) bf16_t Qs[128 * 64];
    __shared__ __align__(16) bf16_t Ks[64 * 64];
    __shared__ __align__(16) bf16_t Vs[64 * 64];   // [d][k]
    __shared__ __align__(16) bf16_t Ps[128 * 64];
    const int qt = blockIdx.x;  // 16
    const int bh = blockIdx.y;  // 32
    const int b = bh >> 4, h = bh & 15;
    const bf16_t* Qb = Q + (size_t)bh * SEQ * HD;
    const bf16_t* Kb = K + (size_t)bh * SEQ * HD;
    const bf16_t* Vb = Vt + (size_t)bh * HD * SEQ;
    const int tid = threadIdx.x;
    const int wave = tid >> 6, lane = tid & 63;
    const int quad = lane >> 4, l16 = lane & 15;
    const int q0 = qt * 128;

    // stage Q tile (contiguous 8192 elements)
    for (int i = 0; i < 4; i++) {
        int e = (i * 256 + tid) * 8;
        *(uint4*)&Qs[e] = *(const uint4*)&Qb[q0 * HD + e];
    }
    __syncthreads();
    shortx8 qf[2][2];
    for (int ti = 0; ti < 2; ti++)
        for (int ks = 0; ks < 2; ks++)
            qf[ti][ks] = *(const shortx8*)&Qs[(wave * 32 + ti * 16 + l16) * 64 + ks * 32 + quad * 8];

    float m_i[2][4], l_i[2][4];
    for (int ti = 0; ti < 2; ti++)
        for (int r = 0; r < 4; r++) { m_i[ti][r] = -1e30f; l_i[ti][r] = 0.f; }
    floatx4 acc_o[2][4] = {};

    for (int k0 = 0; k0 < SEQ; k0 += 64) {
        __syncthreads();
        // stage K tile (contiguous 4096 elems) and V^T tile [64 d][64 k]
        for (int i = 0; i < 2; i++) {
            int e = (i * 256 + tid) * 8;
            *(uint4*)&Ks[e] = *(const uint4*)&Kb[k0 * HD + e];
        }
        for (int i = 0; i < 2; i++) {
            int e = (i * 256 + tid) * 8;
            int d = e >> 6, c = e & 63;
            *(uint4*)&Vs[e] = *(const uint4*)&Vb[d * SEQ + k0 + c];
        }
        __syncthreads();

        // S = Q' K^T  (Q pre-scaled by 1/8)
        floatx4 s[2][4] = {};
        for (int ks = 0; ks < 2; ks++) {
            shortx8 kf[4];
            for (int tj = 0; tj < 4; tj++)
                kf[tj] = *(const shortx8*)&Ks[(tj * 16 + l16) * 64 + ks * 32 + quad * 8];
            for (int ti = 0; ti < 2; ti++)
                for (int tj = 0; tj < 4; tj++)
                    s[ti][tj] = __builtin_amdgcn_mfma_f32_16x16x32_bf16(qf[ti][ks], kf[tj], s[ti][tj], 0, 0, 0);
        }

        // online softmax (wave-local: rows live in this wave's 16-lane groups)
        float alpha[2][4];
        for (int ti = 0; ti < 2; ti++)
            for (int r = 0; r < 4; r++) {
                float mx = fmaxf(fmaxf(s[ti][0][r], s[ti][1][r]), fmaxf(s[ti][2][r], s[ti][3][r]));
                for (int off = 1; off < 16; off <<= 1) mx = fmaxf(mx, __shfl_xor(mx, off, 64));
                float mnew = fmaxf(m_i[ti][r], mx);
                float al = __expf(m_i[ti][r] - mnew);
                m_i[ti][r] = mnew;
                alpha[ti][r] = al;
                float rs = 0.f;
                for (int tj = 0; tj < 4; tj++) {
                    float p = __expf(s[ti][tj][r] - mnew);
                    s[ti][tj][r] = p;
                    rs += p;
                }
                for (int off = 1; off < 16; off <<= 1) rs += __shfl_xor(rs, off, 64);
                l_i[ti][r] = l_i[ti][r] * al + rs;
            }

        // P (C-layout) -> LDS -> A-layout fragments; wave-local rows, no barrier needed
        for (int ti = 0; ti < 2; ti++)
            for (int tj = 0; tj < 4; tj++)
                for (int r = 0; r < 4; r++)
                    Ps[(wave * 32 + ti * 16 + quad * 4 + r) * 64 + tj * 16 + l16] = f2bf(s[ti][tj][r]);

        // rescale O, then O += P V
        for (int ti = 0; ti < 2; ti++)
            for (int tj = 0; tj < 4; tj++)
                for (int r = 0; r < 4; r++)
                    acc_o[ti][tj][r] *= alpha[ti][r];

        for (int ks = 0; ks < 2; ks++) {
            shortx8 pf[2], vf[4];
            for (int ti = 0; ti < 2; ti++)
                pf[ti] = *(const shortx8*)&Ps[(wave * 32 + ti * 16 + l16) * 64 + ks * 32 + quad * 8];
            for (int tj = 0; tj < 4; tj++)
                vf[tj] = *(const shortx8*)&Vs[(tj * 16 + l16) * 64 + ks * 32 + quad * 8];
            for (int ti = 0; ti < 2; ti++)
                for (int tj = 0; tj < 4; tj++)
                    acc_o[ti][tj] = __builtin_amdgcn_mfma_f32_16x16x32_bf16(pf[ti], vf[tj], acc_o[ti][tj], 0, 0, 0);
        }
    }

    // epilogue: normalize and write fp32 out[b][pos][h*64+d]
    for (int ti = 0; ti < 2; ti++)
        for (int tj = 0; tj < 4; tj++)
            for (int r = 0; r < 4; r++) {
                int row = q0 + wave * 32 + ti * 16 + quad * 4 + r;
                float val = acc_o[ti][tj][r] / l_i[ti][r];
                out[((size_t)(b * SEQ + row)) * DM + h * HD + tj * 16 + l16] = val;
            }
}

extern "C" void kernel_launch(void* const* d_in, const int* in_sizes, int n_in,
                              void* d_out, int out_size, void* d_ws, size_t ws_size,
                              hipStream_t stream) {
    const float* tokens = (const float*)d_in[0];
    const float* w = (const float*)d_in[1];
    const float* bias = (const float*)d_in[2];
    float* out = (float*)d_out;
    char* ws = (char*)d_ws;

    bf16_t* tok_bf = (bf16_t*)(ws);                               // 8 MB
    bf16_t* wt_bf  = (bf16_t*)(ws + (size_t)8 * 1024 * 1024);     // 6 MB
    bf16_t* Qb     = (bf16_t*)(ws + (size_t)14 * 1024 * 1024);    // 8 MB
    bf16_t* Kb     = (bf16_t*)(ws + (size_t)22 * 1024 * 1024);    // 8 MB
    bf16_t* Vb     = (bf16_t*)(ws + (size_t)30 * 1024 * 1024);    // 8 MB  (total 38 MB)

    conv_tokens<<<2048, 256, 0, stream>>>(tokens, tok_bf);
    conv_w<<<dim3(48, 16), 256, 0, stream>>>(w, wt_bf);
    qkv_gemm<<<dim3(32, 24), 256, 0, stream>>>(tok_bf, wt_bf, bias, Qb, Kb, Vb);
    attn<<<dim3(16, 32), 256, 0, stream>>>(Qb, Kb, Vb, out);
}

// Round 2
// 203.202 us; speedup vs baseline: 1.4503x; 1.4503x over previous
//
#include <hip/hip_runtime.h>
#include <stdint.h>

typedef __attribute__((ext_vector_type(8))) short shortx8;
typedef __attribute__((ext_vector_type(4))) float floatx4;
typedef unsigned short bf16_t;

#define NH 16
#define HD 64
#define SEQ 2048
#define BATCH 2
#define DM 1024
#define DM3 3072

// async global->LDS, 16B per lane. LDS dest must be wave-uniform-base + lane*16.
#define GLDS(gp, lp) __builtin_amdgcn_global_load_lds( \
    (const __attribute__((address_space(1))) unsigned int*)(gp), \
    (__attribute__((address_space(3))) unsigned int*)(lp), 16, 0, 0)

__device__ __forceinline__ bf16_t f2bf(float f) {
    unsigned int u = __float_as_uint(f);
    u += 0x7fff + ((u >> 16) & 1);   // RTN-even
    return (bf16_t)(u >> 16);
}

// ---------------- tokens fp32 -> bf16 (same layout) ----------------
__global__ __launch_bounds__(256) void conv_tokens(const float* __restrict__ in,
                                                   bf16_t* __restrict__ out) {
    int idx = blockIdx.x * 256 + threadIdx.x;  // 8 elements per thread
    float4 a = ((const float4*)in)[idx * 2];
    float4 b = ((const float4*)in)[idx * 2 + 1];
    uint4 o;
    o.x = (unsigned)f2bf(a.x) | ((unsigned)f2bf(a.y) << 16);
    o.y = (unsigned)f2bf(a.z) | ((unsigned)f2bf(a.w) << 16);
    o.z = (unsigned)f2bf(b.x) | ((unsigned)f2bf(b.y) << 16);
    o.w = (unsigned)f2bf(b.z) | ((unsigned)f2bf(b.w) << 16);
    ((uint4*)out)[idx] = o;
}

// ---------------- w_qkv [1024][3072] fp32 -> wt [3072][1024] bf16 ----------------
__global__ __launch_bounds__(256) void conv_w(const float* __restrict__ w,
                                              bf16_t* __restrict__ wt) {
    __shared__ bf16_t t[64 * 65];
    const int n0 = blockIdx.x * 64;  // 48 blocks
    const int k0 = blockIdx.y * 64;  // 16 blocks
    const int tid = threadIdx.x;
    for (int i = 0; i < 16; i++) {
        int idx = i * 256 + tid;
        int r = idx >> 6, c = idx & 63;
        t[r * 65 + c] = f2bf(w[(k0 + r) * DM3 + n0 + c]);
    }
    __syncthreads();
    for (int i = 0; i < 16; i++) {
        int idx = i * 256 + tid;
        int r = idx >> 6, c = idx & 63;
        wt[(n0 + r) * DM + k0 + c] = t[c * 65 + r];
    }
}

// ---------------- QKV GEMM: [4096x1024] @ wt^T -> Q/K/Vt bf16 ----------------
__global__ __launch_bounds__(256) void qkv_gemm(const bf16_t* __restrict__ A,
                                                const bf16_t* __restrict__ Bt,
                                                const float* __restrict__ bias,
                                                bf16_t* __restrict__ Qo,
                                                bf16_t* __restrict__ Ko,
                                                bf16_t* __restrict__ Vto) {
    __shared__ __align__(16) bf16_t As[128 * 64];
    __shared__ __align__(16) bf16_t Bs[128 * 64];
    const int m0 = blockIdx.x * 128;
    const int n0 = blockIdx.y * 128;
    const int tid = threadIdx.x;
    const int wave = tid >> 6, lane = tid & 63;
    const int quad = lane >> 4, l16 = lane & 15;
    const int wm = (wave & 1) * 64, wn = (wave >> 1) * 64;
    const int srow = tid >> 3, sc8 = (tid & 7) * 8;   // staging row/col-8
    floatx4 acc[4][4] = {};

    for (int kt = 0; kt < DM; kt += 64) {
        __syncthreads();
        for (int rr = 0; rr < 4; rr++) {
            GLDS(&A[(m0 + rr * 32 + srow) * DM + kt + sc8], &As[rr * 2048 + tid * 8]);
            GLDS(&Bt[(n0 + rr * 32 + srow) * DM + kt + sc8], &Bs[rr * 2048 + tid * 8]);
        }
        __syncthreads();
        for (int ks = 0; ks < 2; ks++) {
            shortx8 af[4], bfr[4];
            for (int t = 0; t < 4; t++)
                af[t] = *(const shortx8*)&As[(wm + t * 16 + l16) * 64 + ks * 32 + quad * 8];
            for (int t = 0; t < 4; t++)
                bfr[t] = *(const shortx8*)&Bs[(wn + t * 16 + l16) * 64 + ks * 32 + quad * 8];
            for (int i = 0; i < 4; i++)
                for (int j = 0; j < 4; j++)
                    acc[i][j] = __builtin_amdgcn_mfma_f32_16x16x32_bf16(af[i], bfr[j], acc[i][j], 0, 0, 0);
        }
    }
    // epilogue: bias add, scale Q by 0.125, scatter to head layouts
    for (int i = 0; i < 4; i++)
        for (int j = 0; j < 4; j++)
            for (int r = 0; r < 4; r++) {
                int m = m0 + wm + i * 16 + quad * 4 + r;   // token row
                int n = n0 + wn + j * 16 + l16;            // qkv channel
                float v = acc[i][j][r] + bias[n];
                int part = n >> 10;         // 0=q 1=k 2=v
                int rr = n & 1023;
                int h = rr >> 6, d = rr & 63;
                int b = m >> 11, pos = m & 2047;
                if (part == 0) {
                    Qo[((b * NH + h) * SEQ + pos) * HD + d] = f2bf(v * 0.125f);
                } else if (part == 1) {
                    Ko[((b * NH + h) * SEQ + pos) * HD + d] = f2bf(v);
                } else {
                    Vto[((b * NH + h) * HD + d) * SEQ + pos] = f2bf(v);
                }
            }
}

// ---------------- flash attention, TRANSPOSED: S^T = K·Q^T, O^T = V^T·P^T ----------------
// block = (128 q rows, one bh); 64-key tiles; wave owns 32 q columns.
#define PST 72   // Ps stride in keys (pad 64->72; row = 144B, 16B-aligned)
__global__ __launch_bounds__(256) void attn(const bf16_t* __restrict__ Q,
                                            const bf16_t* __restrict__ K,
                                            const bf16_t* __restrict__ Vt,
                                            float* __restrict__ out) {
    __shared__ __align__(16) bf16_t Qs[128 * 64];
    __shared__ __align__(16) bf16_t Ks[64 * 64];
    __shared__ __align__(16) bf16_t Vs[64 * 64];   // [d][k]
    __shared__ __align__(16) bf16_t Ps[128 * PST]; // [q][key], per-wave private rows
    const int qt_blk = blockIdx.x;  // 16
    const int bh = blockIdx.y;      // 32
    const int b = bh >> 4, h = bh & 15;
    const int q0 = qt_blk * 128;
    const bf16_t* Qb = Q + ((size_t)bh * SEQ + q0) * HD;
    const bf16_t* Kb = K + (size_t)bh * SEQ * HD;
    const bf16_t* Vb = Vt + (size_t)bh * HD * SEQ;
    const int tid = threadIdx.x;
    const int wave = tid >> 6, lane = tid & 63;
    const int quad = lane >> 4, l16 = lane & 15;

    // stage Q tile (16KB contiguous) via async LDS DMA
    for (int rr = 0; rr < 4; rr++)
        GLDS(&Qb[rr * 2048 + tid * 8], &Qs[rr * 2048 + tid * 8]);
    __syncthreads();

    // Q^T B-fragments: B[k=d][n=q]: n=l16 -> q=wave*32+qt*16+l16, k=kc*32+quad*8+j
    shortx8 qf[2][2];
    for (int qt = 0; qt < 2; qt++)
        for (int kc = 0; kc < 2; kc++)
            qf[qt][kc] = *(const shortx8*)&Qs[(wave * 32 + qt * 16 + l16) * 64 + kc * 32 + quad * 8];

    float m_i[2] = {-1e30f, -1e30f}, l_i[2] = {0.f, 0.f};
    floatx4 acc_o[4][2] = {};   // [dt][qt], O^T[d][q]

    const int vrow = tid >> 3, vc8 = (tid & 7) * 8;  // V staging: d-row, key-offset
    for (int k0 = 0; k0 < SEQ; k0 += 64) {
        __syncthreads();
        // K tile: 8KB contiguous; V^T tile: [64 d][64 k], row-scattered global
        for (int rr = 0; rr < 2; rr++) {
            GLDS(&Kb[k0 * 64 + rr * 2048 + tid * 8], &Ks[rr * 2048 + tid * 8]);
            GLDS(&Vb[(size_t)(rr * 32 + vrow) * SEQ + k0 + vc8], &Vs[rr * 2048 + tid * 8]);
        }
        __syncthreads();

        // S^T[key][q] = K·Q^T : A = K[key][d] (m=key=l16), B = Q^T (n=q=l16)
        floatx4 s[4][2] = {};   // [kt][qt]
        for (int kc = 0; kc < 2; kc++) {
            shortx8 kf[4];
            for (int kt = 0; kt < 4; kt++)
                kf[kt] = *(const shortx8*)&Ks[(kt * 16 + l16) * 64 + kc * 32 + quad * 8];
            for (int kt = 0; kt < 4; kt++)
                for (int qt = 0; qt < 2; qt++)
                    s[kt][qt] = __builtin_amdgcn_mfma_f32_16x16x32_bf16(kf[kt], qf[qt][kc], s[kt][qt], 0, 0, 0);
        }

        // online softmax over keys: 16 values in-lane + 2 cross-quad shuffles
        float alpha[2];
        for (int qt = 0; qt < 2; qt++) {
            float mx = -1e30f;
            for (int kt = 0; kt < 4; kt++)
                for (int r = 0; r < 4; r++) mx = fmaxf(mx, s[kt][qt][r]);
            mx = fmaxf(mx, __shfl_xor(mx, 16, 64));
            mx = fmaxf(mx, __shfl_xor(mx, 32, 64));
            float mnew = fmaxf(m_i[qt], mx);
            float al = __expf(m_i[qt] - mnew);
            m_i[qt] = mnew;
            alpha[qt] = al;
            float rs = 0.f;
            for (int kt = 0; kt < 4; kt++)
                for (int r = 0; r < 4; r++) {
                    float p = __expf(s[kt][qt][r] - mnew);
                    s[kt][qt][r] = p;
                    rs += p;
                }
            rs += __shfl_xor(rs, 16, 64);
            rs += __shfl_xor(rs, 32, 64);
            l_i[qt] = l_i[qt] * al + rs;
        }

        // P^T -> Ps[q][key]: 4 consecutive keys per reg group -> packed b64 writes
        for (int qt = 0; qt < 2; qt++)
            for (int kt = 0; kt < 4; kt++) {
                ushort4 pk;
                pk.x = f2bf(s[kt][qt][0]);
                pk.y = f2bf(s[kt][qt][1]);
                pk.z = f2bf(s[kt][qt][2]);
                pk.w = f2bf(s[kt][qt][3]);
                *(ushort4*)&Ps[(wave * 32 + qt * 16 + l16) * PST + kt * 16 + quad * 4] = pk;
            }

        // rescale O^T
        for (int dt = 0; dt < 4; dt++)
            for (int qt = 0; qt < 2; qt++)
                for (int r = 0; r < 4; r++) acc_o[dt][qt][r] *= alpha[qt];

        // O^T += V^T · P^T  (A = V^T[d][key], m=d=l16; B = P^T, n=q=l16)
        for (int kc = 0; kc < 2; kc++) {
            shortx8 vf[4], pf[2];
            for (int dt = 0; dt < 4; dt++)
                vf[dt] = *(const shortx8*)&Vs[(dt * 16 + l16) * 64 + kc * 32 + quad * 8];
            for (int qt = 0; qt < 2; qt++)
                pf[qt] = *(const shortx8*)&Ps[(wave * 32 + qt * 16 + l16) * PST + kc * 32 + quad * 8];
            for (int dt = 0; dt < 4; dt++)
                for (int qt = 0; qt < 2; qt++)
                    acc_o[dt][qt] = __builtin_amdgcn_mfma_f32_16x16x32_bf16(vf[dt], pf[qt], acc_o[dt][qt], 0, 0, 0);
        }
    }

    // epilogue: O^T[d][q] -> out[b][q][h*64+d]; 4 consecutive d -> float4 store
    for (int qt = 0; qt < 2; qt++) {
        float inv = 1.0f / l_i[qt];
        int q = q0 + wave * 32 + qt * 16 + l16;
        for (int dt = 0; dt < 4; dt++) {
            float4 o;
            o.x = acc_o[dt][qt][0] * inv;
            o.y = acc_o[dt][qt][1] * inv;
            o.z = acc_o[dt][qt][2] * inv;
            o.w = acc_o[dt][qt][3] * inv;
            *(float4*)&out[(size_t)(b * SEQ + q) * DM + h * HD + dt * 16 + quad * 4] = o;
        }
    }
}

extern "C" void kernel_launch(void* const* d_in, const int* in_sizes, int n_in,
                              void* d_out, int out_size, void* d_ws, size_t ws_size,
                              hipStream_t stream) {
    const float* tokens = (const float*)d_in[0];
    const float* w = (const float*)d_in[1];
    const float* bias = (const float*)d_in[2];
    float* out = (float*)d_out;
    char* ws = (char*)d_ws;

    bf16_t* tok_bf = (bf16_t*)(ws);                               // 8 MB
    bf16_t* wt_bf  = (bf16_t*)(ws + (size_t)8 * 1024 * 1024);     // 6 MB
    bf16_t* Qb     = (bf16_t*)(ws + (size_t)14 * 1024 * 1024);    // 8 MB
    bf16_t* Kb     = (bf16_t*)(ws + (size_t)22 * 1024 * 1024);    // 8 MB
    bf16_t* Vb     = (bf16_t*)(ws + (size_t)30 * 1024 * 1024);    // 8 MB  (total 38 MB)

    conv_tokens<<<2048, 256, 0, stream>>>(tokens, tok_bf);
    conv_w<<<dim3(48, 16), 256, 0, stream>>>(w, wt_bf);
    qkv_gemm<<<dim3(32, 24), 256, 0, stream>>>(tok_bf, wt_bf, bias, Qb, Kb, Vb);
    attn<<<dim3(16, 32), 256, 0, stream>>>(Qb, Kb, Vb, out);
}

// Round 3
// 188.743 us; speedup vs baseline: 1.5614x; 1.0766x over previous
//
#include <hip/hip_runtime.h>
#include <stdint.h>

typedef __attribute__((ext_vector_type(8))) short shortx8;
typedef __attribute__((ext_vector_type(4))) float floatx4;
typedef unsigned short bf16_t;

#define NH 16
#define HD 64
#define SEQ 2048
#define BATCH 2
#define DM 1024
#define DM3 3072

// async global->LDS, 16B per lane. LDS dest is wave-uniform base + lane*16;
// global side is a per-lane gather, so we can permute source addresses.
#define GLDS(gp, lp) __builtin_amdgcn_global_load_lds( \
    (const __attribute__((address_space(1))) unsigned int*)(gp), \
    (__attribute__((address_space(3))) unsigned int*)(lp), 16, 0, 0)

__device__ __forceinline__ bf16_t f2bf(float f) {
    unsigned int u = __float_as_uint(f);
    u += 0x7fff + ((u >> 16) & 1);   // RTN-even
    return (bf16_t)(u >> 16);
}
// round-half-up, for P in [0,1] (cheaper: 2 VALU ops)
__device__ __forceinline__ bf16_t f2bf_fast(float f) {
    return (bf16_t)((__float_as_uint(f) + 0x8000u) >> 16);
}

// ---------------- tokens fp32 -> bf16 (same layout) ----------------
__global__ __launch_bounds__(256) void conv_tokens(const float* __restrict__ in,
                                                   bf16_t* __restrict__ out) {
    int idx = blockIdx.x * 256 + threadIdx.x;  // 8 elements per thread
    float4 a = ((const float4*)in)[idx * 2];
    float4 b = ((const float4*)in)[idx * 2 + 1];
    uint4 o;
    o.x = (unsigned)f2bf(a.x) | ((unsigned)f2bf(a.y) << 16);
    o.y = (unsigned)f2bf(a.z) | ((unsigned)f2bf(a.w) << 16);
    o.z = (unsigned)f2bf(b.x) | ((unsigned)f2bf(b.y) << 16);
    o.w = (unsigned)f2bf(b.z) | ((unsigned)f2bf(b.w) << 16);
    ((uint4*)out)[idx] = o;
}

// ---------------- w_qkv [1024][3072] fp32 -> wt [3072][1024] bf16 ----------------
__global__ __launch_bounds__(256) void conv_w(const float* __restrict__ w,
                                              bf16_t* __restrict__ wt) {
    __shared__ bf16_t t[64 * 65];
    const int n0 = blockIdx.x * 64;  // 48 blocks
    const int k0 = blockIdx.y * 64;  // 16 blocks
    const int tid = threadIdx.x;
    for (int i = 0; i < 16; i++) {
        int idx = i * 256 + tid;
        int r = idx >> 6, c = idx & 63;
        t[r * 65 + c] = f2bf(w[(k0 + r) * DM3 + n0 + c]);
    }
    __syncthreads();
    for (int i = 0; i < 16; i++) {
        int idx = i * 256 + tid;
        int r = idx >> 6, c = idx & 63;
        wt[(n0 + r) * DM + k0 + c] = t[c * 65 + r];
    }
}

// Swizzle: 64-elt LDS row = 8 groups of 8 bf16; row R group g stored at g^(R&7).
// Staging lane tid: row r=tid>>3, phys group pg=tid&7 -> fetch logical group pg^(r&7).

// ---------------- QKV GEMM: [4096x1024] @ wt^T -> Q/K/Vt bf16 ----------------
#define QSCALE 0.18033688011f   // 0.125 * log2(e): softmax done in log2 domain
__global__ __launch_bounds__(256) void qkv_gemm(const bf16_t* __restrict__ A,
                                                const bf16_t* __restrict__ Bt,
                                                const float* __restrict__ bias,
                                                bf16_t* __restrict__ Qo,
                                                bf16_t* __restrict__ Ko,
                                                bf16_t* __restrict__ Vto) {
    __shared__ __align__(16) bf16_t As[128 * 64];
    __shared__ __align__(16) bf16_t Bs[128 * 64];
    const int m0 = blockIdx.x * 128;
    const int n0 = blockIdx.y * 128;
    const int tid = threadIdx.x;
    const int wave = tid >> 6, lane = tid & 63;
    const int quad = lane >> 4, l16 = lane & 15;
    const int wm = (wave & 1) * 64, wn = (wave >> 1) * 64;
    const int srow = tid >> 3;
    const int swz8 = ((tid & 7) ^ (srow & 7)) * 8;   // swizzled source col
    const int h3 = l16 & 7;
    floatx4 acc[4][4] = {};

    for (int kt = 0; kt < DM; kt += 64) {
        __syncthreads();
        for (int rr = 0; rr < 4; rr++) {
            GLDS(&A[(m0 + rr * 32 + srow) * DM + kt + swz8], &As[rr * 2048 + tid * 8]);
            GLDS(&Bt[(n0 + rr * 32 + srow) * DM + kt + swz8], &Bs[rr * 2048 + tid * 8]);
        }
        __syncthreads();
        for (int ks = 0; ks < 2; ks++) {
            const int g = ((ks * 4 + quad) ^ h3) * 8;
            shortx8 af[4], bfr[4];
            for (int t = 0; t < 4; t++)
                af[t] = *(const shortx8*)&As[(wm + t * 16 + l16) * 64 + g];
            for (int t = 0; t < 4; t++)
                bfr[t] = *(const shortx8*)&Bs[(wn + t * 16 + l16) * 64 + g];
            for (int i = 0; i < 4; i++)
                for (int j = 0; j < 4; j++)
                    acc[i][j] = __builtin_amdgcn_mfma_f32_16x16x32_bf16(af[i], bfr[j], acc[i][j], 0, 0, 0);
        }
    }
    // epilogue: bias add, scale Q by 0.125*log2e, scatter to head layouts
    for (int i = 0; i < 4; i++)
        for (int j = 0; j < 4; j++)
            for (int r = 0; r < 4; r++) {
                int m = m0 + wm + i * 16 + quad * 4 + r;   // token row
                int n = n0 + wn + j * 16 + l16;            // qkv channel
                float v = acc[i][j][r] + bias[n];
                int part = n >> 10;         // 0=q 1=k 2=v
                int rr = n & 1023;
                int h = rr >> 6, d = rr & 63;
                int b = m >> 11, pos = m & 2047;
                if (part == 0) {
                    Qo[((b * NH + h) * SEQ + pos) * HD + d] = f2bf(v * QSCALE);
                } else if (part == 1) {
                    Ko[((b * NH + h) * SEQ + pos) * HD + d] = f2bf(v);
                } else {
                    Vto[((b * NH + h) * HD + d) * SEQ + pos] = f2bf(v);
                }
            }
}

// ---------------- flash attention, TRANSPOSED: S^T = K·Q^T, O^T = V^T·P^T ----------------
// block = (128 q rows, one bh); 64-key tiles; wave owns 32 q columns.
__global__ __launch_bounds__(256) void attn(const bf16_t* __restrict__ Q,
                                            const bf16_t* __restrict__ K,
                                            const bf16_t* __restrict__ Vt,
                                            float* __restrict__ out) {
    __shared__ __align__(16) bf16_t Qs[128 * 64];
    __shared__ __align__(16) bf16_t Ks[64 * 64];
    __shared__ __align__(16) bf16_t Vs[64 * 64];   // [d][k]
    __shared__ __align__(16) bf16_t Ps[128 * 64];  // [q][key], swizzled
    const int qt_blk = blockIdx.x;  // 16
    const int bh = blockIdx.y;      // 32
    const int b = bh >> 4, h = bh & 15;
    const int q0 = qt_blk * 128;
    const bf16_t* Qb = Q + ((size_t)bh * SEQ + q0) * HD;
    const bf16_t* Kb = K + (size_t)bh * SEQ * HD;
    const bf16_t* Vb = Vt + (size_t)bh * HD * SEQ;
    const int tid = threadIdx.x;
    const int wave = tid >> 6, lane = tid & 63;
    const int quad = lane >> 4, l16 = lane & 15;
    const int h3 = l16 & 7;
    const int srow = tid >> 3;
    const int swz8 = ((tid & 7) ^ (srow & 7)) * 8;

    // stage Q tile (16KB) via async LDS DMA, swizzled
    for (int rr = 0; rr < 4; rr++)
        GLDS(&Qb[(rr * 32 + srow) * 64 + swz8], &Qs[rr * 2048 + tid * 8]);
    __syncthreads();

    // Q^T B-fragments: n=q=l16, k=kc*32+quad*8+j
    shortx8 qf[2][2];
    for (int qt = 0; qt < 2; qt++)
        for (int kc = 0; kc < 2; kc++)
            qf[qt][kc] = *(const shortx8*)&Qs[(wave * 32 + qt * 16 + l16) * 64 + ((kc * 4 + quad) ^ h3) * 8];

    float m_i[2] = {-1e30f, -1e30f}, l_i[2] = {0.f, 0.f};
    floatx4 acc_o[4][2] = {};   // [dt][qt], O^T[d][q]

    for (int k0 = 0; k0 < SEQ; k0 += 64) {
        __syncthreads();
        for (int rr = 0; rr < 2; rr++) {
            GLDS(&Kb[(k0 + rr * 32 + srow) * 64 + swz8], &Ks[rr * 2048 + tid * 8]);
            GLDS(&Vb[(size_t)(rr * 32 + srow) * SEQ + k0 + swz8], &Vs[rr * 2048 + tid * 8]);
        }
        __syncthreads();

        // S^T[key][q] = K·Q^T : A = K[key][d] (m=key), B = Q^T (n=q)
        floatx4 s[4][2] = {};   // [kt][qt]
        for (int kc = 0; kc < 2; kc++) {
            const int g = ((kc * 4 + quad) ^ h3) * 8;
            shortx8 kf[4];
            for (int kt = 0; kt < 4; kt++)
                kf[kt] = *(const shortx8*)&Ks[(kt * 16 + l16) * 64 + g];
            for (int kt = 0; kt < 4; kt++)
                for (int qt = 0; qt < 2; qt++)
                    s[kt][qt] = __builtin_amdgcn_mfma_f32_16x16x32_bf16(kf[kt], qf[qt][kc], s[kt][qt], 0, 0, 0);
        }

        // online softmax over keys (log2 domain): 16 in-lane + 2 cross-quad shuffles
        float alpha[2];
        for (int qt = 0; qt < 2; qt++) {
            float mx = -1e30f;
            for (int kt = 0; kt < 4; kt++)
                for (int r = 0; r < 4; r++) mx = fmaxf(mx, s[kt][qt][r]);
            mx = fmaxf(mx, __shfl_xor(mx, 16, 64));
            mx = fmaxf(mx, __shfl_xor(mx, 32, 64));
            float mnew = fmaxf(m_i[qt], mx);
            float al = __builtin_amdgcn_exp2f(m_i[qt] - mnew);
            m_i[qt] = mnew;
            alpha[qt] = al;
            float rs = 0.f;
            for (int kt = 0; kt < 4; kt++)
                for (int r = 0; r < 4; r++) {
                    float p = __builtin_amdgcn_exp2f(s[kt][qt][r] - mnew);
                    s[kt][qt][r] = p;
                    rs += p;
                }
            rs += __shfl_xor(rs, 16, 64);
            rs += __shfl_xor(rs, 32, 64);
            l_i[qt] = l_i[qt] * al + rs;
        }

        // P^T -> Ps[q][key] (swizzled): keys kt*16+quad*4..+3 -> group 2kt+(quad>>1), sub (quad&1)*4
        for (int qt = 0; qt < 2; qt++)
            for (int kt = 0; kt < 4; kt++) {
                ushort4 pk;
                pk.x = f2bf_fast(s[kt][qt][0]);
                pk.y = f2bf_fast(s[kt][qt][1]);
                pk.z = f2bf_fast(s[kt][qt][2]);
                pk.w = f2bf_fast(s[kt][qt][3]);
                *(ushort4*)&Ps[(wave * 32 + qt * 16 + l16) * 64 +
                               ((2 * kt + (quad >> 1)) ^ h3) * 8 + (quad & 1) * 4] = pk;
            }

        // rescale O^T
        for (int dt = 0; dt < 4; dt++)
            for (int qt = 0; qt < 2; qt++)
                for (int r = 0; r < 4; r++) acc_o[dt][qt][r] *= alpha[qt];

        // O^T += V^T · P^T  (A = V^T[d][key], m=d; B = P^T, n=q)
        for (int kc = 0; kc < 2; kc++) {
            const int g = ((kc * 4 + quad) ^ h3) * 8;
            shortx8 vf[4], pf[2];
            for (int dt = 0; dt < 4; dt++)
                vf[dt] = *(const shortx8*)&Vs[(dt * 16 + l16) * 64 + g];
            for (int qt = 0; qt < 2; qt++)
                pf[qt] = *(const shortx8*)&Ps[(wave * 32 + qt * 16 + l16) * 64 + g];
            for (int dt = 0; dt < 4; dt++)
                for (int qt = 0; qt < 2; qt++)
                    acc_o[dt][qt] = __builtin_amdgcn_mfma_f32_16x16x32_bf16(vf[dt], pf[qt], acc_o[dt][qt], 0, 0, 0);
        }
    }

    // epilogue: O^T[d][q] -> out[b][q][h*64+d]; 4 consecutive d -> float4 store
    for (int qt = 0; qt < 2; qt++) {
        float inv = 1.0f / l_i[qt];
        int q = q0 + wave * 32 + qt * 16 + l16;
        for (int dt = 0; dt < 4; dt++) {
            float4 o;
            o.x = acc_o[dt][qt][0] * inv;
            o.y = acc_o[dt][qt][1] * inv;
            o.z = acc_o[dt][qt][2] * inv;
            o.w = acc_o[dt][qt][3] * inv;
            *(float4*)&out[(size_t)(b * SEQ + q) * DM + h * HD + dt * 16 + quad * 4] = o;
        }
    }
}

extern "C" void kernel_launch(void* const* d_in, const int* in_sizes, int n_in,
                              void* d_out, int out_size, void* d_ws, size_t ws_size,
                              hipStream_t stream) {
    const float* tokens = (const float*)d_in[0];
    const float* w = (const float*)d_in[1];
    const float* bias = (const float*)d_in[2];
    float* out = (float*)d_out;
    char* ws = (char*)d_ws;

    bf16_t* tok_bf = (bf16_t*)(ws);                               // 8 MB
    bf16_t* wt_bf  = (bf16_t*)(ws + (size_t)8 * 1024 * 1024);     // 6 MB
    bf16_t* Qb     = (bf16_t*)(ws + (size_t)14 * 1024 * 1024);    // 8 MB
    bf16_t* Kb     = (bf16_t*)(ws + (size_t)22 * 1024 * 1024);    // 8 MB
    bf16_t* Vb     = (bf16_t*)(ws + (size_t)30 * 1024 * 1024);    // 8 MB  (total 38 MB)

    conv_tokens<<<2048, 256, 0, stream>>>(tokens, tok_bf);
    conv_w<<<dim3(48, 16), 256, 0, stream>>>(w, wt_bf);
    qkv_gemm<<<dim3(32, 24), 256, 0, stream>>>(tok_bf, wt_bf, bias, Qb, Kb, Vb);
    attn<<<dim3(16, 32), 256, 0, stream>>>(Qb, Kb, Vb, out);
}